// Round 1
// baseline (731.787 us; speedup 1.0000x reference)
//
#include <hip/hip_runtime.h>

#define BB 16
#define CC 512
#define NN 192
#define CS 128
#define CR 64
#define INTER 12800
#define BN1 3072
#define EPSF 1e-5f

// workspace layout (floats)
#define OFF_LIN_TH 0
#define OFF_LIN_PH (OFF_LIN_TH + BB*CS*NN)   // 393216
#define OFF_A      (OFF_LIN_PH + BB*CS*NN)   // 786432
#define OFF_B      (OFF_A + BB*CR*NN)        // 983040
#define OFF_P      (OFF_B + BB*CR*NN)        // 1179648
#define OFF_QT     (OFF_P + BB*CR*NN)        // 1376256   qT[b][j][o]
#define OFF_ATT    (OFF_QT + BB*CR*NN)       // 1572864   att_pre[b][c][n]
#define OFF_STH    (OFF_ATT + BB*CC*NN)      // 3145728   th_sum128 th_sq128 ph_sum128 ph_sq128
#define OFF_ROWA   (OFF_STH + 512)           // rowA1024 rowAsq1024 rowB1024 rowBsq1024
#define OFF_SATT   (OFF_ROWA + 4096)         // att_sum512 att_sq512
#define OFF_SCL    (OFF_SATT + 1024)         // th_a128 th_d128 ph_a128 ph_d128 rel_s64 rel_sh64 att_a512 att_d512

// K1: lin_th/lin_ph[b,cs,n] = sum_c W[cs,c] * inputs[b,c,n]   (biases cancel in BN)
__global__ __launch_bounds__(256) void k1_lin(
    const float* __restrict__ x, const float* __restrict__ wth,
    const float* __restrict__ wph, float* __restrict__ oth,
    float* __restrict__ oph)
{
  int bid = blockIdx.x;
  int path = bid / 48; int rem = bid - path*48;
  int b = rem / 3, n0 = (rem - b*3) * 64;
  const float* w = path ? wph : wth;
  float* out = path ? oph : oth;
  int tid = threadIdx.x;
  int ty = tid >> 4, tx = tid & 15;
  __shared__ float Xs[32][64];
  __shared__ float Ws[32][132];
  float acc[8][4];
  #pragma unroll
  for (int i=0;i<8;++i)
    #pragma unroll
    for(int j=0;j<4;++j) acc[i][j]=0.f;
  for (int c0 = 0; c0 < CC; c0 += 32) {
    __syncthreads();
    {
      int nn = tid & 63, cb = tid >> 6;
      #pragma unroll
      for (int it = 0; it < 8; ++it)
        Xs[cb + it*4][nn] = x[b*CC*NN + (c0 + cb + it*4)*NN + n0 + nn];
    }
    {
      int cc = tid & 31, sb = tid >> 5;
      #pragma unroll
      for (int it = 0; it < 16; ++it)
        Ws[cc][sb + it*8] = w[(sb + it*8)*CC + c0 + cc];
    }
    __syncthreads();
    #pragma unroll 8
    for (int cc = 0; cc < 32; ++cc) {
      float x4[4], w8[8];
      #pragma unroll
      for (int j=0;j<4;++j) x4[j] = Xs[cc][tx*4+j];
      #pragma unroll
      for (int i=0;i<8;++i) w8[i] = Ws[cc][ty*8+i];
      #pragma unroll
      for (int i=0;i<8;++i)
        #pragma unroll
        for (int j=0;j<4;++j) acc[i][j] += w8[i]*x4[j];
    }
  }
  #pragma unroll
  for (int i=0;i<8;++i) {
    int cs = ty*8+i;
    float4 v = make_float4(acc[i][0],acc[i][1],acc[i][2],acc[i][3]);
    *reinterpret_cast<float4*>(&out[b*CS*NN + cs*NN + n0 + tx*4]) = v;
  }
}

// K2: per-channel sum/sumsq over (b,n) for lin_th / lin_ph
__global__ __launch_bounds__(256) void k2_stats(
    const float* __restrict__ lt, const float* __restrict__ lp,
    float* __restrict__ st)
{
  int idx = blockIdx.x;            // 256: path*128 + cs
  int path = idx >> 7, cs = idx & 127;
  const float* src = (path ? lp : lt) + cs*NN;
  int tid = threadIdx.x;
  float s=0.f, q=0.f;
  for (int e = tid; e < BN1; e += 256) {
    int b = e / NN, n = e - b*NN;
    float v = src[b*CS*NN + n];
    s += v; q += v*v;
  }
  __shared__ float rs[4], rq[4];
  #pragma unroll
  for (int off=32; off; off>>=1){ s += __shfl_down(s,off); q += __shfl_down(q,off); }
  int w = tid >> 6;
  if ((tid & 63)==0){ rs[w]=s; rq[w]=q; }
  __syncthreads();
  if (tid==0){
    s = rs[0]+rs[1]+rs[2]+rs[3]; q = rq[0]+rq[1]+rq[2]+rq[3];
    st[path*256 + cs] = s; st[path*256 + 128 + cs] = q;
  }
}

__global__ void k2_fin(const float* __restrict__ st,
    const float* __restrict__ tg, const float* __restrict__ tbe,
    const float* __restrict__ pg, const float* __restrict__ pbe,
    float* __restrict__ scl)
{
  int t = threadIdx.x;
  if (t < 128) {
    float mean = st[t] * (1.f/3072.f);
    float var = st[128+t] * (1.f/3072.f) - mean*mean;
    float a = tg[t] * rsqrtf(var + EPSF);
    scl[t] = a; scl[128+t] = tbe[t] - mean*a;
  } else if (t < 256) {
    int c = t - 128;
    float mean = st[256+c] * (1.f/3072.f);
    float var = st[384+c] * (1.f/3072.f) - mean*mean;
    float a = pg[c] * rsqrtf(var + EPSF);
    scl[256+c] = a; scl[384+c] = pbe[c] - mean*a;
  }
}

// K3: A[b,o,i] = sum_c re_w[o,c]*relu(bn(lin_th)),  B likewise from lin_ph
__global__ __launch_bounds__(256) void k3_ab(
    const float* __restrict__ lt, const float* __restrict__ lp,
    const float* __restrict__ scl, const float* __restrict__ rw,
    float* __restrict__ A, float* __restrict__ Bq)
{
  int bid = blockIdx.x;            // 1536
  int path = bid / 768; int rem = bid - path*768;
  int b = rem / 48; int chunk = rem - b*48;
  int idx = chunk*256 + threadIdx.x;   // o*NN + i
  int o = idx / NN, i = idx - o*NN;
  const float* lin = path ? lp : lt;
  const float* sc = scl + path*256;
  float acc = 0.f;
  for (int c = 0; c < CS; ++c) {
    float v = fmaxf(sc[c]*lin[b*CS*NN + c*NN + i] + sc[128+c], 0.f);
    acc += rw[o*CS + c] * v;
  }
  (path ? Bq : A)[b*CR*NN + idx] = acc;
}

// K3b: per-(b,o) row sum/sumsq of A and B
__global__ __launch_bounds__(64) void k3_rows(
    const float* __restrict__ A, const float* __restrict__ Bq,
    float* __restrict__ rows)
{
  int bid = blockIdx.x;            // 2048: path*1024 + b*64+o
  int path = bid >> 10; int r = bid & 1023;
  const float* src = path ? Bq : A;
  int t = threadIdx.x;
  float s=0.f,q=0.f;
  #pragma unroll
  for (int it=0; it<3; ++it){
    float v = src[r*NN + t + it*64];
    s += v; q += v*v;
  }
  #pragma unroll
  for (int off=32; off; off>>=1){ s+=__shfl_down(s,off); q+=__shfl_down(q,off); }
  if (t==0){ rows[path*2048 + r] = s; rows[path*2048 + 1024 + r] = q; }
}

// K4a: rel-BN closed form from row sums
__global__ void k4_relstats(const float* __restrict__ rows,
    const float* __restrict__ rg, const float* __restrict__ rbe,
    float* __restrict__ scl)
{
  int o = threadIdx.x;  // 64
  float sa=0,saq=0,sb=0,sbq=0,cross=0;
  for (int b=0;b<BB;++b){
    float ra = rows[b*64+o];
    float rb = rows[2048 + b*64+o];
    sa += ra; sb += rb; cross += ra*rb;
    saq += rows[1024 + b*64+o];
    sbq += rows[3072 + b*64+o];
  }
  float mean = (sa - sb) * (1.f/3072.f);                      // /(B*N)
  float e2 = (saq + sbq) * (1.f/3072.f) - cross * (2.f/589824.f); // /(B*N), /(B*N*N)
  float var = e2 - mean*mean;
  float s = rg[o] * rsqrtf(var + EPSF);
  scl[512+o] = s;
  scl[576+o] = rbe[o] - s*mean;
}

// K4b: p = s*A + sh ; qT[b][j][o] = s*B[b][o][j]
__global__ __launch_bounds__(256) void k4_pq(
    const float* __restrict__ A, const float* __restrict__ Bq,
    const float* __restrict__ scl, float* __restrict__ p,
    float* __restrict__ qT)
{
  int idx = blockIdx.x*256 + threadIdx.x;  // 1536 blocks
  const int TOT = BB*CR*NN;
  int path = idx / TOT; int e = idx - path*TOT;
  int b = e / (CR*NN); int rem = e - b*(CR*NN);
  int o = rem / NN; int j = rem - o*NN;
  if (path == 0) p[e] = scl[512+o]*A[e] + scl[576+o];
  else qT[b*NN*CR + j*CR + o] = scl[512+o]*Bq[e];
}

// K5: att_pre[b,o2,n] = sum_k cat[b,n,k]*att_w[o2,k], R generated on the fly
__global__ __launch_bounds__(256) void k5_gemm(
    const float* __restrict__ x, const float* __restrict__ p,
    const float* __restrict__ qT, const float* __restrict__ aw,
    float* __restrict__ att)
{
  int bid = blockIdx.x;            // 768 = 16b * 8 o2t * 3 nt * 2 ksplit
  int ks = bid & 1; int t = bid >> 1;
  int b = t / 24; int r = t - b*24;
  int o20 = (r/3)*64; int n0 = (r - (r/3)*3)*64;
  int tid = threadIdx.x; int ty = tid >> 4, tx = tid & 15;
  __shared__ float Wt[64][68];   // [k][o2]
  __shared__ float Rt[64][68];   // [k][n]
  __shared__ float Ps[64][64];   // p[b][o][n0+nn]
  __shared__ float qs[64];
  {
    int nn = tid & 63, ob = tid >> 6;
    #pragma unroll
    for (int it = 0; it < 16; ++it)
      Ps[ob + it*4][nn] = p[b*CR*NN + (ob + it*4)*NN + n0 + nn];
  }
  float acc[4][4];
  #pragma unroll
  for (int i=0;i<4;++i)
    #pragma unroll
    for (int j=0;j<4;++j) acc[i][j]=0.f;
  int kt0 = ks*100;
  for (int kt = kt0; kt < kt0 + 100; ++kt) {
    int k0 = kt * 64;
    __syncthreads();
    {   // stage Wt[kk][oo] = aw[(o20+oo)*INTER + k0+kk]
      int m = tid & 15, ob = tid >> 4;
      #pragma unroll
      for (int rr = 0; rr < 4; ++rr) {
        int oo = ob + rr*16;
        float4 v = *reinterpret_cast<const float4*>(&aw[(o20+oo)*INTER + k0 + m*4]);
        Wt[m*4+0][oo] = v.x; Wt[m*4+1][oo] = v.y;
        Wt[m*4+2][oo] = v.z; Wt[m*4+3][oo] = v.w;
      }
    }
    if (kt < 8) {   // xt part: R = inputs[b, c, n]
      int nn = tid & 63, kb = tid >> 6;
      #pragma unroll
      for (int it = 0; it < 16; ++it)
        Rt[kb + it*4][nn] = x[b*CC*NN + (k0 + kb + it*4)*NN + n0 + nn];
    } else {        // rel part: R[o][n] = relu(p[o,n]-q[o,j])
      int j = kt - 8;
      if (tid < 64) qs[tid] = qT[b*NN*CR + j*CR + tid];
      __syncthreads();
      int nn = tid & 63, ob = tid >> 6;
      #pragma unroll
      for (int it = 0; it < 16; ++it) {
        int o = ob + it*4;
        Rt[o][nn] = fmaxf(Ps[o][nn] - qs[o], 0.f);
      }
    }
    __syncthreads();
    #pragma unroll 16
    for (int kk = 0; kk < 64; ++kk) {
      float a4[4], b4[4];
      *reinterpret_cast<float4*>(a4) = *reinterpret_cast<const float4*>(&Wt[kk][ty*4]);
      *reinterpret_cast<float4*>(b4) = *reinterpret_cast<const float4*>(&Rt[kk][tx*4]);
      #pragma unroll
      for (int i=0;i<4;++i)
        #pragma unroll
        for (int j=0;j<4;++j) acc[i][j] += a4[i]*b4[j];
    }
  }
  #pragma unroll
  for (int i=0;i<4;++i) {
    int o2 = o20 + ty*4 + i;
    #pragma unroll
    for (int j=0;j<4;++j)
      atomicAdd(&att[b*CC*NN + o2*NN + n0 + tx*4 + j], acc[i][j]);  // 2 writers: order-independent
  }
}

// K6: att BN stats
__global__ __launch_bounds__(256) void k6_stats(
    const float* __restrict__ att, float* __restrict__ st)
{
  int o2 = blockIdx.x;   // 512
  int tid = threadIdx.x;
  float s=0.f, q=0.f;
  for (int e = tid; e < BN1; e += 256) {
    int b = e / NN, n = e - b*NN;
    float v = att[b*CC*NN + o2*NN + n];
    s += v; q += v*v;
  }
  __shared__ float rs[4], rq[4];
  #pragma unroll
  for (int off=32; off; off>>=1){ s += __shfl_down(s,off); q += __shfl_down(q,off); }
  int w = tid >> 6;
  if ((tid & 63)==0){ rs[w]=s; rq[w]=q; }
  __syncthreads();
  if (tid==0){
    s = rs[0]+rs[1]+rs[2]+rs[3]; q = rq[0]+rq[1]+rq[2]+rq[3];
    st[o2] = s; st[512+o2] = q;
  }
}

__global__ void k6_fin(const float* __restrict__ st,
    const float* __restrict__ g, const float* __restrict__ be,
    float* __restrict__ scl)
{
  int c = threadIdx.x;  // 512
  float mean = st[c] * (1.f/3072.f);
  float var = st[512+c] * (1.f/3072.f) - mean*mean;
  float a = g[c] * rsqrtf(var + EPSF);
  scl[640+c] = a;
  scl[1152+c] = be[c] - mean*a;
}

// K7: out[b,c] = sum_n sig*x / sum_n sig
__global__ __launch_bounds__(64) void k7_out(
    const float* __restrict__ att, const float* __restrict__ x,
    const float* __restrict__ scl, float* __restrict__ out)
{
  int row = blockIdx.x;   // 8192
  int b = row >> 9, c = row & 511;
  int t = threadIdx.x;
  float a = scl[640+c], d = scl[1152+c];
  float sf=0.f, ss=0.f;
  #pragma unroll
  for (int it=0;it<3;++it){
    int n = t + it*64;
    float v = att[b*CC*NN + c*NN + n];
    float sig = 1.f/(1.f + expf(-(a*v + d)));
    sf += sig * x[b*CC*NN + c*NN + n];
    ss += sig;
  }
  #pragma unroll
  for (int off=32; off; off>>=1){ sf+=__shfl_down(sf,off); ss+=__shfl_down(ss,off); }
  if (t==0) out[row] = sf/ss;
}

extern "C" void kernel_launch(void* const* d_in, const int* in_sizes, int n_in,
                              void* d_out, int out_size, void* d_ws, size_t ws_size,
                              hipStream_t stream)
{
  const float* inputs  = (const float*)d_in[0];
  // d_in[1] = retain (always 0 in this setup)
  const float* theta_w = (const float*)d_in[2];
  const float* theta_g = (const float*)d_in[4];
  const float* theta_be= (const float*)d_in[5];
  const float* phi_w   = (const float*)d_in[6];
  const float* phi_g   = (const float*)d_in[8];
  const float* phi_be  = (const float*)d_in[9];
  const float* re_w    = (const float*)d_in[10];
  const float* re_g    = (const float*)d_in[12];
  const float* re_be   = (const float*)d_in[13];
  const float* att_w   = (const float*)d_in[14];
  const float* att_g   = (const float*)d_in[16];
  const float* att_be  = (const float*)d_in[17];

  float* ws = (float*)d_ws;
  float* lin_th = ws + OFF_LIN_TH;
  float* lin_ph = ws + OFF_LIN_PH;
  float* Abuf   = ws + OFF_A;
  float* Bbuf   = ws + OFF_B;
  float* pbuf   = ws + OFF_P;
  float* qTbuf  = ws + OFF_QT;
  float* attp   = ws + OFF_ATT;
  float* sth    = ws + OFF_STH;
  float* rows   = ws + OFF_ROWA;
  float* satt   = ws + OFF_SATT;
  float* scl    = ws + OFF_SCL;

  hipMemsetAsync(attp, 0, (size_t)BB*CC*NN*sizeof(float), stream);

  k1_lin<<<96, 256, 0, stream>>>(inputs, theta_w, phi_w, lin_th, lin_ph);
  k2_stats<<<256, 256, 0, stream>>>(lin_th, lin_ph, sth);
  k2_fin<<<1, 256, 0, stream>>>(sth, theta_g, theta_be, phi_g, phi_be, scl);
  k3_ab<<<1536, 256, 0, stream>>>(lin_th, lin_ph, scl, re_w, Abuf, Bbuf);
  k3_rows<<<2048, 64, 0, stream>>>(Abuf, Bbuf, rows);
  k4_relstats<<<1, 64, 0, stream>>>(rows, re_g, re_be, scl);
  k4_pq<<<1536, 256, 0, stream>>>(Abuf, Bbuf, scl, pbuf, qTbuf);
  k5_gemm<<<768, 256, 0, stream>>>(inputs, pbuf, qTbuf, att_w, attp);
  k6_stats<<<512, 256, 0, stream>>>(attp, satt);
  k6_fin<<<1, 512, 0, stream>>>(satt, att_g, att_be, scl);
  k7_out<<<8192, 64, 0, stream>>>(attp, inputs, scl, (float*)d_out);
}

// Round 2
// 200.355 us; speedup vs baseline: 3.6524x; 3.6524x over previous
//
#include <hip/hip_runtime.h>

#define BB 16
#define CC 512
#define NN 192
#define CS 128
#define CR 64
#define EPSF 1e-5f

typedef __attribute__((ext_vector_type(8))) short short8;
typedef __attribute__((ext_vector_type(4))) float f32x4;
typedef __attribute__((ext_vector_type(4))) unsigned int uint4v;

// ---------------- workspace layout (float units) ----------------
#define OFF_LIN_TH 0
#define OFF_LIN_PH (OFF_LIN_TH + BB*CS*NN)     // 393216
#define OFF_A      (OFF_LIN_PH + BB*CS*NN)     // 786432
#define OFF_B      (OFF_A + BB*CR*NN)          // 983040
#define OFF_P2     (OFF_B + BB*CR*NN)          // 1179648  p2[b][n][o]
#define OFF_QT     (OFF_P2 + BB*CR*NN)         // 1376256  qT[b][j][o]
#define OFF_ATTF   (OFF_QT + BB*CR*NN)         // 1572864  att_pre summed [b][c][n]
#define PART       (BB*CC*NN)                  // 1572864
#define OFF_ATTP   (OFF_ATTF + PART)           // 3145728  5 partial buffers
#define OFF_WBF    (OFF_ATTP + 5*PART)         // 11010048 (short[512*12288] = 3145728 floats)
#define OFF_STH    (OFF_WBF + 3145728)         // 14155776
#define OFF_ROWA   (OFF_STH + 512)
#define OFF_SATT   (OFF_ROWA + 4096)
#define OFF_SCL    (OFF_SATT + 1024)

__device__ __forceinline__ unsigned pkbf(float a, float b){
  unsigned r; asm("v_cvt_pk_bf16_f32 %0, %1, %2" : "=v"(r) : "v"(a), "v"(b)); return r;
}

__device__ __forceinline__ void gload_lds16(const void* g, void* l){
  __builtin_amdgcn_global_load_lds(
      (const __attribute__((address_space(1))) unsigned int*)g,
      (__attribute__((address_space(3))) unsigned int*)l, 16, 0, 0);
}

// K1: lin_th/lin_ph[b,cs,n] = sum_c W[cs,c] * inputs[b,c,n]
__global__ __launch_bounds__(256) void k1_lin(
    const float* __restrict__ x, const float* __restrict__ wth,
    const float* __restrict__ wph, float* __restrict__ oth,
    float* __restrict__ oph)
{
  int bid = blockIdx.x;
  int path = bid / 48; int rem = bid - path*48;
  int b = rem / 3, n0 = (rem - b*3) * 64;
  const float* w = path ? wph : wth;
  float* out = path ? oph : oth;
  int tid = threadIdx.x;
  int ty = tid >> 4, tx = tid & 15;
  __shared__ float Xs[32][64];
  __shared__ float Ws[32][132];
  float acc[8][4];
  #pragma unroll
  for (int i=0;i<8;++i)
    #pragma unroll
    for(int j=0;j<4;++j) acc[i][j]=0.f;
  for (int c0 = 0; c0 < CC; c0 += 32) {
    __syncthreads();
    {
      int nn = tid & 63, cb = tid >> 6;
      #pragma unroll
      for (int it = 0; it < 8; ++it)
        Xs[cb + it*4][nn] = x[b*CC*NN + (c0 + cb + it*4)*NN + n0 + nn];
    }
    {
      int cc = tid & 31, sb = tid >> 5;
      #pragma unroll
      for (int it = 0; it < 16; ++it)
        Ws[cc][sb + it*8] = w[(sb + it*8)*CC + c0 + cc];
    }
    __syncthreads();
    #pragma unroll 8
    for (int cc = 0; cc < 32; ++cc) {
      float x4[4], w8[8];
      #pragma unroll
      for (int j=0;j<4;++j) x4[j] = Xs[cc][tx*4+j];
      #pragma unroll
      for (int i=0;i<8;++i) w8[i] = Ws[cc][ty*8+i];
      #pragma unroll
      for (int i=0;i<8;++i)
        #pragma unroll
        for (int j=0;j<4;++j) acc[i][j] += w8[i]*x4[j];
    }
  }
  #pragma unroll
  for (int i=0;i<8;++i) {
    int cs = ty*8+i;
    float4 v = make_float4(acc[i][0],acc[i][1],acc[i][2],acc[i][3]);
    *reinterpret_cast<float4*>(&out[b*CS*NN + cs*NN + n0 + tx*4]) = v;
  }
}

// K2: per-channel sum/sumsq over (b,n) for lin_th / lin_ph
__global__ __launch_bounds__(256) void k2_stats(
    const float* __restrict__ lt, const float* __restrict__ lp,
    float* __restrict__ st)
{
  int idx = blockIdx.x;            // 256: path*128 + cs
  int path = idx >> 7, cs = idx & 127;
  const float* src = (path ? lp : lt) + cs*NN;
  int tid = threadIdx.x;
  float s=0.f, q=0.f;
  for (int e = tid; e < BB*NN; e += 256) {
    int b = e / NN, n = e - b*NN;
    float v = src[b*CS*NN + n];
    s += v; q += v*v;
  }
  __shared__ float rs[4], rq[4];
  #pragma unroll
  for (int off=32; off; off>>=1){ s += __shfl_down(s,off); q += __shfl_down(q,off); }
  int w = tid >> 6;
  if ((tid & 63)==0){ rs[w]=s; rq[w]=q; }
  __syncthreads();
  if (tid==0){
    s = rs[0]+rs[1]+rs[2]+rs[3]; q = rq[0]+rq[1]+rq[2]+rq[3];
    st[path*256 + cs] = s; st[path*256 + 128 + cs] = q;
  }
}

__global__ void k2_fin(const float* __restrict__ st,
    const float* __restrict__ tg, const float* __restrict__ tbe,
    const float* __restrict__ pg, const float* __restrict__ pbe,
    float* __restrict__ scl)
{
  int t = threadIdx.x;
  if (t < 128) {
    float mean = st[t] * (1.f/3072.f);
    float var = st[128+t] * (1.f/3072.f) - mean*mean;
    float a = tg[t] * rsqrtf(var + EPSF);
    scl[t] = a; scl[128+t] = tbe[t] - mean*a;
  } else if (t < 256) {
    int c = t - 128;
    float mean = st[256+c] * (1.f/3072.f);
    float var = st[384+c] * (1.f/3072.f) - mean*mean;
    float a = pg[c] * rsqrtf(var + EPSF);
    scl[256+c] = a; scl[384+c] = pbe[c] - mean*a;
  }
}

// K3: A[b,o,i] = sum_c re_w[o,c]*relu(bn(lin_th)),  B likewise from lin_ph
__global__ __launch_bounds__(256) void k3_ab(
    const float* __restrict__ lt, const float* __restrict__ lp,
    const float* __restrict__ scl, const float* __restrict__ rw,
    float* __restrict__ A, float* __restrict__ Bq)
{
  int bid = blockIdx.x;            // 1536
  int path = bid / 768; int rem = bid - path*768;
  int b = rem / 48; int chunk = rem - b*48;
  int idx = chunk*256 + threadIdx.x;   // o*NN + i
  int o = idx / NN, i = idx - o*NN;
  const float* lin = path ? lp : lt;
  const float* sc = scl + path*256;
  float acc = 0.f;
  for (int c = 0; c < CS; ++c) {
    float v = fmaxf(sc[c]*lin[b*CS*NN + c*NN + i] + sc[128+c], 0.f);
    acc += rw[o*CS + c] * v;
  }
  (path ? Bq : A)[b*CR*NN + idx] = acc;
}

// K3b: per-(b,o) row sum/sumsq of A and B
__global__ __launch_bounds__(64) void k3_rows(
    const float* __restrict__ A, const float* __restrict__ Bq,
    float* __restrict__ rows)
{
  int bid = blockIdx.x;            // 2048: path*1024 + b*64+o
  int path = bid >> 10; int r = bid & 1023;
  const float* src = path ? Bq : A;
  int t = threadIdx.x;
  float s=0.f,q=0.f;
  #pragma unroll
  for (int it=0; it<3; ++it){
    float v = src[r*NN + t + it*64];
    s += v; q += v*v;
  }
  #pragma unroll
  for (int off=32; off; off>>=1){ s+=__shfl_down(s,off); q+=__shfl_down(q,off); }
  if (t==0){ rows[path*2048 + r] = s; rows[path*2048 + 1024 + r] = q; }
}

// K4a: rel-BN closed form from row sums
__global__ void k4_relstats(const float* __restrict__ rows,
    const float* __restrict__ rg, const float* __restrict__ rbe,
    float* __restrict__ scl)
{
  int o = threadIdx.x;  // 64
  float sa=0,saq=0,sb=0,sbq=0,cross=0;
  for (int b=0;b<BB;++b){
    float ra = rows[b*64+o];
    float rb = rows[2048 + b*64+o];
    sa += ra; sb += rb; cross += ra*rb;
    saq += rows[1024 + b*64+o];
    sbq += rows[3072 + b*64+o];
  }
  float mean = (sa - sb) * (1.f/3072.f);
  float e2 = (saq + sbq) * (1.f/3072.f) - cross * (2.f/589824.f);
  float var = e2 - mean*mean;
  float s = rg[o] * rsqrtf(var + EPSF);
  scl[512+o] = s;
  scl[576+o] = rbe[o] - s*mean;
}

// K4b: p2[b][n][o] = s*A[b][o][n] + sh ; qT[b][j][o] = s*B[b][o][j]
__global__ __launch_bounds__(256) void k4_pq(
    const float* __restrict__ A, const float* __restrict__ Bq,
    const float* __restrict__ scl, float* __restrict__ p2,
    float* __restrict__ qT)
{
  int idx = blockIdx.x*256 + threadIdx.x;  // 1536 blocks
  const int TOT = BB*CR*NN;
  int path = idx / TOT; int e = idx - path*TOT;
  int b = e / (CR*NN); int rem = e - b*(CR*NN);
  if (path == 0) {
    int n = rem >> 6, o = rem & 63;
    p2[e] = scl[512+o]*A[b*CR*NN + o*NN + n] + scl[576+o];
  } else {
    int j = rem >> 6, o = rem & 63;
    qT[e] = scl[512+o]*Bq[b*CR*NN + o*NN + j];
  }
}

// KCONV: att_w rel-columns -> bf16, wbf[o2][kk], kk = k-512, stride 12288
__global__ __launch_bounds__(256) void kconv(
    const float* __restrict__ aw, short* __restrict__ wbf)
{
  int t = blockIdx.x*256 + threadIdx.x;     // 786432 threads, 8 elems each
  int o2 = t / 1536;
  int kk = (t - o2*1536) * 8;
  const float* src = &aw[o2*12800 + 512 + kk];
  float4 v0 = *reinterpret_cast<const float4*>(src);
  float4 v1 = *reinterpret_cast<const float4*>(src+4);
  uint4v w;
  w.x = pkbf(v0.x, v0.y); w.y = pkbf(v0.z, v0.w);
  w.z = pkbf(v1.x, v1.y); w.w = pkbf(v1.z, v1.w);
  *reinterpret_cast<uint4v*>(&wbf[o2*12288 + kk]) = w;
}

// KX: x-part of att GEMM (k<512), f32: out[b,o2,n] = sum_c aw[o2,c]*x[b,c,n]
__global__ __launch_bounds__(256) void kx_lin(
    const float* __restrict__ x, const float* __restrict__ aw,
    float* __restrict__ out)
{
  int bid = blockIdx.x;            // 192 = 16b * 4mt * 3nt
  int b = bid / 12; int rem = bid - b*12;
  int mt = rem / 3, nt = rem - mt*3;
  int o2b = mt*128, n0 = nt*64;
  int tid = threadIdx.x;
  int ty = tid >> 4, tx = tid & 15;
  __shared__ float Xs[32][64];
  __shared__ float Ws[32][132];
  float acc[8][4];
  #pragma unroll
  for (int i=0;i<8;++i)
    #pragma unroll
    for(int j=0;j<4;++j) acc[i][j]=0.f;
  for (int c0 = 0; c0 < CC; c0 += 32) {
    __syncthreads();
    {
      int nn = tid & 63, cb = tid >> 6;
      #pragma unroll
      for (int it = 0; it < 8; ++it)
        Xs[cb + it*4][nn] = x[b*CC*NN + (c0 + cb + it*4)*NN + n0 + nn];
    }
    {
      int cc = tid & 31, sb = tid >> 5;
      #pragma unroll
      for (int it = 0; it < 16; ++it)
        Ws[cc][sb + it*8] = aw[(o2b + sb + it*8)*12800 + c0 + cc];
    }
    __syncthreads();
    #pragma unroll 8
    for (int cc = 0; cc < 32; ++cc) {
      float x4[4], w8[8];
      #pragma unroll
      for (int j=0;j<4;++j) x4[j] = Xs[cc][tx*4+j];
      #pragma unroll
      for (int i=0;i<8;++i) w8[i] = Ws[cc][ty*8+i];
      #pragma unroll
      for (int i=0;i<8;++i)
        #pragma unroll
        for (int j=0;j<4;++j) acc[i][j] += w8[i]*x4[j];
    }
  }
  #pragma unroll
  for (int i=0;i<8;++i) {
    int cs = ty*8+i;
    float4 v = make_float4(acc[i][0],acc[i][1],acc[i][2],acc[i][3]);
    *reinterpret_cast<float4*>(&out[(b*CC + o2b + cs)*NN + n0 + tx*4]) = v;
  }
}

// K5: rel-part att GEMM via bf16 MFMA.
// Block tile 128(o2) x 96(n), K-tile = 64 (= one j), 48 j per block (ksplit 4).
// B-tile relu(p-q) generated in LDS from register-resident p + LDS q.
__global__ __launch_bounds__(256, 2) void k5_mfma(
    const short* __restrict__ wbf, const float* __restrict__ p2,
    const float* __restrict__ qT, float* __restrict__ attp)
{
  int bid = blockIdx.x;            // 512 = ks(4) * b(16) * mt(4) * nt(2)
  int nt = bid & 1, mt = (bid >> 1) & 3, b = (bid >> 3) & 15, ks = bid >> 7;
  int o20 = mt*128, n0 = nt*96;
  int j0 = ks*48;

  int tid = threadIdx.x;
  int w = tid >> 6, lane = tid & 63;
  int wr = w >> 1, wc = w & 1;
  int l15 = lane & 15, l4 = lane >> 4;

  __shared__ __align__(16) short As[128*64];   // [row][chunk'] 8 chunks of 8 bf16, XOR-swz
  __shared__ __align__(16) short Bs[96*64];
  __shared__ __align__(16) float qlds[2][64];

  // register-resident p for this block's 3 gen-chunks
  float pr[3][8];
  #pragma unroll
  for (int it=0; it<3; ++it){
    int ch = it*256 + tid;
    int n = ch >> 3, c = ch & 7;
    const float* pp = &p2[((b*NN) + n0 + n)*64 + c*8];
    float4 u0 = *reinterpret_cast<const float4*>(pp);
    float4 u1 = *reinterpret_cast<const float4*>(pp+4);
    pr[it][0]=u0.x; pr[it][1]=u0.y; pr[it][2]=u0.z; pr[it][3]=u0.w;
    pr[it][4]=u1.x; pr[it][5]=u1.y; pr[it][6]=u1.z; pr[it][7]=u1.w;
  }
  if (tid < 64) qlds[0][tid] = qT[(b*NN + j0)*64 + tid];

  f32x4 zero = {0.f,0.f,0.f,0.f};
  f32x4 acc[4][3];
  #pragma unroll
  for (int mi=0;mi<4;++mi)
    #pragma unroll
    for (int ni=0;ni<3;++ni) acc[mi][ni] = zero;

  for (int kt = 0; kt < 48; ++kt) {
    int j = j0 + kt;
    __syncthreads();
    // stage A tile (W) async: wave w covers rows w*32..w*32+31
    #pragma unroll
    for (int it=0; it<4; ++it){
      int cp = w*256 + it*64 + lane;
      int row = cp >> 3, cpr = cp & 7;
      int c = cpr ^ (row & 7);
      gload_lds16(&wbf[(o20 + row)*12288 + j*64 + c*8],
                  &As[(w*256 + it*64)*8]);
    }
    // prefetch next q
    if (tid < 64 && kt < 47) qlds[(kt+1)&1][tid] = qT[(b*NN + j + 1)*64 + tid];
    // generate B tile: Bs[n][kk] = relu(p[n][kk] - q[kk]) in bf16, XOR-swz
    {
      const float* qq = qlds[kt&1];
      #pragma unroll
      for (int it=0; it<3; ++it){
        int ch = it*256 + tid;
        int n = ch >> 3, c = ch & 7;
        float4 q0 = *reinterpret_cast<const float4*>(&qq[c*8]);
        float4 q1 = *reinterpret_cast<const float4*>(&qq[c*8+4]);
        float r0 = fmaxf(pr[it][0]-q0.x, 0.f);
        float r1 = fmaxf(pr[it][1]-q0.y, 0.f);
        float r2 = fmaxf(pr[it][2]-q0.z, 0.f);
        float r3 = fmaxf(pr[it][3]-q0.w, 0.f);
        float r4 = fmaxf(pr[it][4]-q1.x, 0.f);
        float r5 = fmaxf(pr[it][5]-q1.y, 0.f);
        float r6 = fmaxf(pr[it][6]-q1.z, 0.f);
        float r7 = fmaxf(pr[it][7]-q1.w, 0.f);
        uint4v wv;
        wv.x = pkbf(r0,r1); wv.y = pkbf(r2,r3);
        wv.z = pkbf(r4,r5); wv.w = pkbf(r6,r7);
        *reinterpret_cast<uint4v*>(&Bs[n*64 + ((c ^ (n&7))<<3)]) = wv;
      }
    }
    __syncthreads();   // drains vmcnt (As) + lgkm (Bs)
    // MFMA: wave quadrant 64x48
    #pragma unroll
    for (int s=0; s<2; ++s){
      short8 av[4], bv[3];
      int c = s*4 + l4;
      #pragma unroll
      for (int mi=0; mi<4; ++mi){
        int row = wr*64 + mi*16 + l15;
        av[mi] = *reinterpret_cast<const short8*>(&As[row*64 + ((c ^ (row&7))<<3)]);
      }
      #pragma unroll
      for (int ni=0; ni<3; ++ni){
        int rown = wc*48 + ni*16 + l15;
        bv[ni] = *reinterpret_cast<const short8*>(&Bs[rown*64 + ((c ^ (rown&7))<<3)]);
      }
      #pragma unroll
      for (int mi=0; mi<4; ++mi)
        #pragma unroll
        for (int ni=0; ni<3; ++ni)
          acc[mi][ni] = __builtin_amdgcn_mfma_f32_16x16x32_bf16(av[mi], bv[ni], acc[mi][ni], 0, 0, 0);
    }
  }

  // epilogue: write partial ks
  float* dst = attp + (size_t)ks*PART;
  #pragma unroll
  for (int mi=0; mi<4; ++mi){
    #pragma unroll
    for (int r=0; r<4; ++r){
      int o2 = o20 + wr*64 + mi*16 + l4*4 + r;
      #pragma unroll
      for (int ni=0; ni<3; ++ni){
        int n = n0 + wc*48 + ni*16 + l15;
        dst[(b*CC + o2)*NN + n] = acc[mi][ni][r];
      }
    }
  }
}

// K6: sum 5 partials -> attf, plus BN stats per channel
__global__ __launch_bounds__(256) void k6_stats(
    const float* __restrict__ attp, float* __restrict__ attf,
    float* __restrict__ st)
{
  int o2 = blockIdx.x;   // 512
  int tid = threadIdx.x;
  float s=0.f, q=0.f;
  for (int e = tid; e < BB*NN; e += 256) {
    int b = e / NN, n = e - b*NN;
    int idx = (b*CC + o2)*NN + n;
    float v = attp[idx] + attp[PART+idx] + attp[2*PART+idx]
            + attp[3*PART+idx] + attp[4*PART+idx];
    attf[idx] = v;
    s += v; q += v*v;
  }
  __shared__ float rs[4], rq[4];
  #pragma unroll
  for (int off=32; off; off>>=1){ s += __shfl_down(s,off); q += __shfl_down(q,off); }
  int w = tid >> 6;
  if ((tid & 63)==0){ rs[w]=s; rq[w]=q; }
  __syncthreads();
  if (tid==0){
    s = rs[0]+rs[1]+rs[2]+rs[3]; q = rq[0]+rq[1]+rq[2]+rq[3];
    st[o2] = s; st[512+o2] = q;
  }
}

__global__ void k6_fin(const float* __restrict__ st,
    const float* __restrict__ g, const float* __restrict__ be,
    float* __restrict__ scl)
{
  int c = threadIdx.x;  // 512
  float mean = st[c] * (1.f/3072.f);
  float var = st[512+c] * (1.f/3072.f) - mean*mean;
  float a = g[c] * rsqrtf(var + EPSF);
  scl[640+c] = a;
  scl[1152+c] = be[c] - mean*a;
}

// K7: out[b,c] = sum_n sig*x / sum_n sig
__global__ __launch_bounds__(64) void k7_out(
    const float* __restrict__ attf, const float* __restrict__ x,
    const float* __restrict__ scl, float* __restrict__ out)
{
  int row = blockIdx.x;   // 8192
  int b = row >> 9, c = row & 511;
  int t = threadIdx.x;
  float a = scl[640+c], d = scl[1152+c];
  float sf=0.f, ss=0.f;
  #pragma unroll
  for (int it=0;it<3;++it){
    int n = t + it*64;
    float v = attf[b*CC*NN + c*NN + n];
    float sig = 1.f/(1.f + expf(-(a*v + d)));
    sf += sig * x[b*CC*NN + c*NN + n];
    ss += sig;
  }
  #pragma unroll
  for (int off=32; off; off>>=1){ sf+=__shfl_down(sf,off); ss+=__shfl_down(ss,off); }
  if (t==0) out[row] = sf/ss;
}

extern "C" void kernel_launch(void* const* d_in, const int* in_sizes, int n_in,
                              void* d_out, int out_size, void* d_ws, size_t ws_size,
                              hipStream_t stream)
{
  const float* inputs  = (const float*)d_in[0];
  const float* theta_w = (const float*)d_in[2];
  const float* theta_g = (const float*)d_in[4];
  const float* theta_be= (const float*)d_in[5];
  const float* phi_w   = (const float*)d_in[6];
  const float* phi_g   = (const float*)d_in[8];
  const float* phi_be  = (const float*)d_in[9];
  const float* re_w    = (const float*)d_in[10];
  const float* re_g    = (const float*)d_in[12];
  const float* re_be   = (const float*)d_in[13];
  const float* att_w   = (const float*)d_in[14];
  const float* att_g   = (const float*)d_in[16];
  const float* att_be  = (const float*)d_in[17];

  float* ws = (float*)d_ws;
  float* lin_th = ws + OFF_LIN_TH;
  float* lin_ph = ws + OFF_LIN_PH;
  float* Abuf   = ws + OFF_A;
  float* Bbuf   = ws + OFF_B;
  float* p2buf  = ws + OFF_P2;
  float* qTbuf  = ws + OFF_QT;
  float* attf   = ws + OFF_ATTF;
  float* attp   = ws + OFF_ATTP;
  short* wbf    = (short*)(ws + OFF_WBF);
  float* sth    = ws + OFF_STH;
  float* rows   = ws + OFF_ROWA;
  float* satt   = ws + OFF_SATT;
  float* scl    = ws + OFF_SCL;

  kconv<<<3072, 256, 0, stream>>>(att_w, wbf);
  k1_lin<<<96, 256, 0, stream>>>(inputs, theta_w, phi_w, lin_th, lin_ph);
  k2_stats<<<256, 256, 0, stream>>>(lin_th, lin_ph, sth);
  k2_fin<<<1, 256, 0, stream>>>(sth, theta_g, theta_be, phi_g, phi_be, scl);
  k3_ab<<<1536, 256, 0, stream>>>(lin_th, lin_ph, scl, re_w, Abuf, Bbuf);
  k3_rows<<<2048, 64, 0, stream>>>(Abuf, Bbuf, rows);
  k4_relstats<<<1, 64, 0, stream>>>(rows, re_g, re_be, scl);
  k4_pq<<<1536, 256, 0, stream>>>(Abuf, Bbuf, scl, p2buf, qTbuf);
  kx_lin<<<192, 256, 0, stream>>>(inputs, att_w, attp + 4*(size_t)PART);
  k5_mfma<<<512, 256, 0, stream>>>(wbf, p2buf, qTbuf, attp);
  k6_stats<<<512, 256, 0, stream>>>(attp, attf, satt);
  k6_fin<<<1, 512, 0, stream>>>(satt, att_g, att_be, scl);
  k7_out<<<8192, 64, 0, stream>>>(attf, inputs, scl, (float*)d_out);
}

// Round 3
// 151.810 us; speedup vs baseline: 4.8204x; 1.3198x over previous
//
#include <hip/hip_runtime.h>

#define BB 16
#define CC 512
#define NN 192
#define CS 128
#define CR 64
#define EPSF 1e-5f
#define PART (BB*CC*NN)                    // 1572864

typedef __attribute__((ext_vector_type(8))) short short8;
typedef __attribute__((ext_vector_type(4))) float f32x4;
typedef __attribute__((ext_vector_type(4))) unsigned int uint4v;

// ---------------- workspace layout (float units) ----------------
#define OFF_LIN2  0                        // 786432  [b][256][192] (th rows 0-127, ph 128-255)
#define OFF_RL    786432                   // 786432  relu'd lin2
#define OFF_ATTPX 0                        // alias: lin2+rl dead by the time kx writes (1572864)
#define OFF_A     1572864                  // 196608  A[b][o][i]
#define OFF_B     1769472                  // 196608
#define OFF_P2    1966080                  // 196608  p2[b][n][o]
#define OFF_QT    2162688                  // 196608  qT[b][j][o]
#define OFF_ATTF  2359296                  // 1572864 summed att_pre
#define OFF_ATTP3 3932160                  // 3*1572864 partials ks=1..3
#define OFF_WBF   8650752                  // 3276800 (short[512*12800])
#define OFF_XT    11927552                 // 786432  (short[16*192*512]) xT bf16
#define OFF_ROWS  12713984                 // 4096
#define OFF_SCL   12718080                 // 1664

__device__ __forceinline__ unsigned pkbf(float a, float b){
  unsigned r; asm("v_cvt_pk_bf16_f32 %0, %1, %2" : "=v"(r) : "v"(a), "v"(b)); return r;
}

__device__ __forceinline__ void gload_lds16(const void* g, void* l){
  __builtin_amdgcn_global_load_lds(
      (const __attribute__((address_space(1))) unsigned int*)g,
      (__attribute__((address_space(3))) unsigned int*)l, 16, 0, 0);
}

// KCONV: att_w [512][12800] -> bf16 wbf (full rows)
__global__ __launch_bounds__(256) void kconv(
    const float* __restrict__ aw, short* __restrict__ wbf)
{
  int t = blockIdx.x*256 + threadIdx.x;     // 819200 threads, 8 elems each
  int o2 = t / 1600;
  int kk = (t - o2*1600) * 8;
  const float* src = &aw[o2*12800 + kk];
  float4 v0 = *reinterpret_cast<const float4*>(src);
  float4 v1 = *reinterpret_cast<const float4*>(src+4);
  uint4v w;
  w.x = pkbf(v0.x, v0.y); w.y = pkbf(v0.z, v0.w);
  w.z = pkbf(v1.x, v1.y); w.w = pkbf(v1.z, v1.w);
  *reinterpret_cast<uint4v*>(&wbf[o2*12800 + kk]) = w;
}

// KXT: inputs [b][c][n] f32 -> xT [b][n][c] bf16 (LDS transpose)
__global__ __launch_bounds__(256) void kxt(
    const float* __restrict__ x, short* __restrict__ xT)
{
  int bid = blockIdx.x;            // 384 = b16 * ct8 * nt3
  int nt = bid % 3; int ct = (bid/3) & 7; int b = bid / 24;
  int c0 = ct*64, n0 = nt*64;
  __shared__ float Ts[64][65];
  int tid = threadIdx.x;
  int col = tid & 63, r0 = tid >> 6;
  #pragma unroll
  for (int it = 0; it < 16; ++it){
    int r = r0 + it*4;
    Ts[r][col] = x[(b*CC + c0 + r)*NN + n0 + col];
  }
  __syncthreads();
  #pragma unroll
  for (int it = 0; it < 2; ++it){
    int cp = it*256 + tid;
    int nr = cp >> 3, cc8 = (cp & 7)*8;
    uint4v wv;
    wv.x = pkbf(Ts[cc8+0][nr], Ts[cc8+1][nr]);
    wv.y = pkbf(Ts[cc8+2][nr], Ts[cc8+3][nr]);
    wv.z = pkbf(Ts[cc8+4][nr], Ts[cc8+5][nr]);
    wv.w = pkbf(Ts[cc8+6][nr], Ts[cc8+7][nr]);
    *reinterpret_cast<uint4v*>(&xT[((b*NN) + n0 + nr)*CC + c0 + cc8]) = wv;
  }
}

// K1: lin2[b][path*128+cs][n] = sum_c W[cs,c]*x[b,c,n]  (f32, 32x32 tiles)
__global__ __launch_bounds__(256) void k1_lin(
    const float* __restrict__ x, const float* __restrict__ wth,
    const float* __restrict__ wph, float* __restrict__ lin2)
{
  int bid = blockIdx.x;            // 768 = path2 * b16 * ct4 * nt6
  int nt = bid % 6; int ct = (bid/6) & 3; int b = (bid/24) & 15; int path = bid/384;
  int cs0 = ct*32, n0 = nt*32;
  const float* w = path ? wph : wth;
  int tid = threadIdx.x;
  int ty = tid >> 4, tx = tid & 15;
  __shared__ float Xs[32][33];
  __shared__ float Ws[32][36];
  float acc[2][2] = {{0.f,0.f},{0.f,0.f}};
  for (int c0 = 0; c0 < CC; c0 += 32){
    __syncthreads();
    {
      int nn = tid & 31, cb = tid >> 5;
      #pragma unroll
      for (int it = 0; it < 4; ++it)
        Xs[cb + it*8][nn] = x[(b*CC + c0 + cb + it*8)*NN + n0 + nn];
    }
    {
      int cc = tid & 31, sb = tid >> 5;
      #pragma unroll
      for (int it = 0; it < 4; ++it)
        Ws[cc][sb + it*8] = w[(cs0 + sb + it*8)*CC + c0 + cc];
    }
    __syncthreads();
    #pragma unroll 8
    for (int cc = 0; cc < 32; ++cc){
      float w2[2], x2[2];
      w2[0] = Ws[cc][ty*2]; w2[1] = Ws[cc][ty*2+1];
      x2[0] = Xs[cc][tx*2]; x2[1] = Xs[cc][tx*2+1];
      acc[0][0] += w2[0]*x2[0]; acc[0][1] += w2[0]*x2[1];
      acc[1][0] += w2[1]*x2[0]; acc[1][1] += w2[1]*x2[1];
    }
  }
  #pragma unroll
  for (int r = 0; r < 2; ++r){
    int cs = cs0 + ty*2 + r;
    float2 v = make_float2(acc[r][0], acc[r][1]);
    *reinterpret_cast<float2*>(&lin2[(b*256 + path*128 + cs)*NN + n0 + tx*2]) = v;
  }
}

// K2: per-cs2 BN stats over (b,n), fin folded -> scl[cs2], scl[256+cs2]
__global__ __launch_bounds__(256) void k2_stats(
    const float* __restrict__ lin2,
    const float* __restrict__ tg, const float* __restrict__ tbe,
    const float* __restrict__ pg, const float* __restrict__ pbe,
    float* __restrict__ scl)
{
  int cs2 = blockIdx.x;            // 256
  const float* src = lin2 + cs2*NN;
  int tid = threadIdx.x;
  float s=0.f, q=0.f;
  for (int e = tid; e < BB*NN; e += 256){
    int b = e / NN, n = e - b*NN;
    float v = src[b*256*NN + n];
    s += v; q += v*v;
  }
  __shared__ float rs[4], rq[4];
  #pragma unroll
  for (int off=32; off; off>>=1){ s += __shfl_down(s,off); q += __shfl_down(q,off); }
  int w = tid >> 6;
  if ((tid & 63)==0){ rs[w]=s; rq[w]=q; }
  __syncthreads();
  if (tid==0){
    s = rs[0]+rs[1]+rs[2]+rs[3]; q = rq[0]+rq[1]+rq[2]+rq[3];
    float mean = s * (1.f/3072.f);
    float var = q * (1.f/3072.f) - mean*mean;
    int path = cs2 >> 7, c = cs2 & 127;
    float g  = path ? pg[c]  : tg[c];
    float be = path ? pbe[c] : tbe[c];
    float a = g * rsqrtf(var + EPSF);
    scl[cs2] = a; scl[256+cs2] = be - mean*a;
  }
}

// KRELU: rl = relu(a*lin2 + d), vectorized
__global__ __launch_bounds__(256) void krelu(
    const float* __restrict__ lin2, const float* __restrict__ scl,
    float* __restrict__ rl)
{
  int idx = blockIdx.x*256 + threadIdx.x;  // 768 blocks
  int e4 = idx*4;
  int cs2 = (e4 / NN) & 255;
  float a = scl[cs2], d = scl[256+cs2];
  float4 v = *reinterpret_cast<const float4*>(&lin2[e4]);
  float4 r;
  r.x = fmaxf(a*v.x + d, 0.f); r.y = fmaxf(a*v.y + d, 0.f);
  r.z = fmaxf(a*v.z + d, 0.f); r.w = fmaxf(a*v.w + d, 0.f);
  *reinterpret_cast<float4*>(&rl[e4]) = r;
}

// K3: A[b,o,i] = sum_c rw[o,c]*rl_th[b,c,i]; B from rl_ph. LDS-tiled f32.
__global__ __launch_bounds__(256) void k3_gemm(
    const float* __restrict__ rl, const float* __restrict__ rw,
    float* __restrict__ A, float* __restrict__ Bq)
{
  int bid = blockIdx.x;            // 128 = path2 * b16 * ih4
  int ih = bid & 3; int b = (bid>>2) & 15; int path = bid >> 6;
  int i0 = ih*48;
  __shared__ float Ls[128][48];
  __shared__ float Ws[64][132];
  int tid = threadIdx.x;
  #pragma unroll
  for (int it = 0; it < 6; ++it){
    int cp = it*256 + tid;         // 1536 float4
    int row = cp / 12, c4 = cp - row*12;
    *reinterpret_cast<float4*>(&Ls[row][c4*4]) =
      *reinterpret_cast<const float4*>(&rl[(b*256 + path*128 + row)*NN + i0 + c4*4]);
  }
  #pragma unroll
  for (int it = 0; it < 8; ++it){
    int cp = it*256 + tid;         // 2048 float4
    int o = cp >> 5, c4 = cp & 31;
    *reinterpret_cast<float4*>(&Ws[o][c4*4]) =
      *reinterpret_cast<const float4*>(&rw[o*CS + c4*4]);
  }
  __syncthreads();
  int oy = tid >> 4, ix = tid & 15;
  float acc[4][3];
  #pragma unroll
  for (int r=0;r<4;++r)
    #pragma unroll
    for (int e=0;e<3;++e) acc[r][e]=0.f;
  #pragma unroll 4
  for (int c = 0; c < 128; ++c){
    float w4[4], l3[3];
    #pragma unroll
    for (int r=0;r<4;++r) w4[r] = Ws[oy*4+r][c];
    #pragma unroll
    for (int e=0;e<3;++e) l3[e] = Ls[c][ix*3+e];
    #pragma unroll
    for (int r=0;r<4;++r)
      #pragma unroll
      for (int e=0;e<3;++e) acc[r][e] += w4[r]*l3[e];
  }
  float* dst = path ? Bq : A;
  #pragma unroll
  for (int r=0;r<4;++r)
    #pragma unroll
    for (int e=0;e<3;++e)
      dst[(b*CR + oy*4+r)*NN + i0 + ix*3 + e] = acc[r][e];
}

// K3b: per-(b,o) row sum/sumsq of A and B
__global__ __launch_bounds__(64) void k3_rows(
    const float* __restrict__ A, const float* __restrict__ Bq,
    float* __restrict__ rows)
{
  int bid = blockIdx.x;            // 2048: path*1024 + b*64+o
  int path = bid >> 10; int r = bid & 1023;
  const float* src = path ? Bq : A;
  int t = threadIdx.x;
  float s=0.f,q=0.f;
  #pragma unroll
  for (int it=0; it<3; ++it){
    float v = src[r*NN + t + it*64];
    s += v; q += v*v;
  }
  #pragma unroll
  for (int off=32; off; off>>=1){ s+=__shfl_down(s,off); q+=__shfl_down(q,off); }
  if (t==0){ rows[path*2048 + r] = s; rows[path*2048 + 1024 + r] = q; }
}

// K4a: rel-BN closed form from row sums
__global__ void k4_relstats(const float* __restrict__ rows,
    const float* __restrict__ rg, const float* __restrict__ rbe,
    float* __restrict__ scl)
{
  int o = threadIdx.x;  // 64
  float sa=0,saq=0,sb=0,sbq=0,cross=0;
  for (int b=0;b<BB;++b){
    float ra = rows[b*64+o];
    float rb = rows[2048 + b*64+o];
    sa += ra; sb += rb; cross += ra*rb;
    saq += rows[1024 + b*64+o];
    sbq += rows[3072 + b*64+o];
  }
  float mean = (sa - sb) * (1.f/3072.f);
  float e2 = (saq + sbq) * (1.f/3072.f) - cross * (2.f/589824.f);
  float var = e2 - mean*mean;
  float s = rg[o] * rsqrtf(var + EPSF);
  scl[512+o] = s;
  scl[576+o] = rbe[o] - s*mean;
}

// K4b: p2[b][n][o] = s*A[b][o][n] + sh ; qT[b][j][o] = s*B[b][o][j]
__global__ __launch_bounds__(256) void k4_pq(
    const float* __restrict__ A, const float* __restrict__ Bq,
    const float* __restrict__ scl, float* __restrict__ p2,
    float* __restrict__ qT)
{
  int idx = blockIdx.x*256 + threadIdx.x;  // 1536 blocks
  const int TOT = BB*CR*NN;
  int path = idx / TOT; int e = idx - path*TOT;
  int b = e / (CR*NN); int rem = e - b*(CR*NN);
  if (path == 0) {
    int n = rem >> 6, o = rem & 63;
    p2[e] = scl[512+o]*A[b*CR*NN + o*NN + n] + scl[576+o];
  } else {
    int j = rem >> 6, o = rem & 63;
    qT[e] = scl[512+o]*Bq[b*CR*NN + o*NN + j];
  }
}

// GX: x-part att GEMM via MFMA: attpx[b,o2,n] = sum_c aw[o2,c]*x[b,c,n], c<512.
// A,B both staged via swizzled-source global_load_lds; 2-phase counted-vmcnt.
__global__ __launch_bounds__(256) void gx_mfma(
    const short* __restrict__ wbf, const short* __restrict__ xT,
    float* __restrict__ out)
{
  int bid = blockIdx.x;            // 128 = b16 * mt4 * nt2
  int nt = bid & 1, mt = (bid >> 1) & 3, b = bid >> 3;
  int o20 = mt*128, n0 = nt*96;
  int tid = threadIdx.x;
  int w = tid >> 6, lane = tid & 63;
  int wr = w >> 1, wc = w & 1;
  int l15 = lane & 15, l4 = lane >> 4;

  __shared__ __align__(16) short As[2][128*64];
  __shared__ __align__(16) short Bs[2][96*64];

  auto stageA = [&](int buf, int kt){
    #pragma unroll
    for (int it=0; it<4; ++it){
      int cp = w*256 + it*64 + lane;
      int row = cp >> 3, c = (cp & 7) ^ (row & 7);
      gload_lds16(&wbf[(o20 + row)*12800 + kt*64 + c*8],
                  &As[buf][(w*256 + it*64)*8]);
    }
  };
  auto stageB = [&](int buf, int kt){
    #pragma unroll
    for (int it=0; it<3; ++it){
      int cp = w*192 + it*64 + lane;
      int row = cp >> 3, c = (cp & 7) ^ (row & 7);
      gload_lds16(&xT[((b*NN) + n0 + row)*CC + kt*64 + c*8],
                  &Bs[buf][(w*192 + it*64)*8]);
    }
  };

  f32x4 acc[4][3];
  #pragma unroll
  for (int mi=0;mi<4;++mi)
    #pragma unroll
    for (int ni=0;ni<3;++ni) acc[mi][ni] = (f32x4){0.f,0.f,0.f,0.f};

  stageA(0,0); stageB(0,0);
  for (int kt = 0; kt < 8; ++kt){
    int cur = kt & 1;
    if (kt < 7){
      stageA(cur^1, kt+1); stageB(cur^1, kt+1);
      asm volatile("s_waitcnt vmcnt(7)" ::: "memory");
    } else {
      asm volatile("s_waitcnt vmcnt(0)" ::: "memory");
    }
    __builtin_amdgcn_s_barrier();
    #pragma unroll
    for (int s=0; s<2; ++s){
      short8 av[4], bv[3];
      int c = s*4 + l4;
      #pragma unroll
      for (int mi=0; mi<4; ++mi){
        int row = wr*64 + mi*16 + l15;
        av[mi] = *reinterpret_cast<const short8*>(&As[cur][row*64 + ((c ^ (row&7))<<3)]);
      }
      #pragma unroll
      for (int ni=0; ni<3; ++ni){
        int rown = wc*48 + ni*16 + l15;
        bv[ni] = *reinterpret_cast<const short8*>(&Bs[cur][rown*64 + ((c ^ (rown&7))<<3)]);
      }
      #pragma unroll
      for (int mi=0; mi<4; ++mi)
        #pragma unroll
        for (int ni=0; ni<3; ++ni)
          acc[mi][ni] = __builtin_amdgcn_mfma_f32_16x16x32_bf16(av[mi], bv[ni], acc[mi][ni], 0, 0, 0);
    }
    __builtin_amdgcn_s_barrier();
  }
  #pragma unroll
  for (int mi=0; mi<4; ++mi){
    #pragma unroll
    for (int r=0; r<4; ++r){
      int o2 = o20 + wr*64 + mi*16 + l4*4 + r;
      #pragma unroll
      for (int ni=0; ni<3; ++ni){
        int n = n0 + wc*48 + ni*16 + l15;
        out[(b*CC + o2)*NN + n] = acc[mi][ni][r];
      }
    }
  }
}

// K5: rel-part att GEMM, bf16 MFMA, 2-phase pipeline (A dbuf + reg-q prefetch).
__global__ __launch_bounds__(256) void k5_mfma(
    const short* __restrict__ wbf, const float* __restrict__ p2,
    const float* __restrict__ qT, float* __restrict__ attpx,
    float* __restrict__ attp3)
{
  int bid = blockIdx.x;            // 512 = ks4 * b16 * mt4 * nt2
  int nt = bid & 1, mt = (bid >> 1) & 3, b = (bid >> 3) & 15, ks = bid >> 7;
  int o20 = mt*128, n0 = nt*96;
  int j0 = ks*48;

  int tid = threadIdx.x;
  int w = tid >> 6, lane = tid & 63;
  int wr = w >> 1, wc = w & 1;
  int l15 = lane & 15, l4 = lane >> 4;
  int cq = tid & 7;

  __shared__ __align__(16) short As[2][128*64];
  __shared__ __align__(16) short Bs[96*64];

  // register-resident p (3 chunks of 8)
  float pr[3][8];
  #pragma unroll
  for (int it=0; it<3; ++it){
    int n = it*32 + (tid >> 3);
    const float* pp = &p2[((b*NN) + n0 + n)*64 + cq*8];
    float4 u0 = *reinterpret_cast<const float4*>(pp);
    float4 u1 = *reinterpret_cast<const float4*>(pp+4);
    pr[it][0]=u0.x; pr[it][1]=u0.y; pr[it][2]=u0.z; pr[it][3]=u0.w;
    pr[it][4]=u1.x; pr[it][5]=u1.y; pr[it][6]=u1.z; pr[it][7]=u1.w;
  }

  auto stageA = [&](int buf, int j){
    #pragma unroll
    for (int it=0; it<4; ++it){
      int cp = w*256 + it*64 + lane;
      int row = cp >> 3, c = (cp & 7) ^ (row & 7);
      gload_lds16(&wbf[(o20 + row)*12800 + 512 + j*64 + c*8],
                  &As[buf][(w*256 + it*64)*8]);
    }
  };
  auto genB = [&](float4 qa, float4 qb){
    #pragma unroll
    for (int it=0; it<3; ++it){
      float r0 = fmaxf(pr[it][0]-qa.x, 0.f);
      float r1 = fmaxf(pr[it][1]-qa.y, 0.f);
      float r2 = fmaxf(pr[it][2]-qa.z, 0.f);
      float r3 = fmaxf(pr[it][3]-qa.w, 0.f);
      float r4 = fmaxf(pr[it][4]-qb.x, 0.f);
      float r5 = fmaxf(pr[it][5]-qb.y, 0.f);
      float r6 = fmaxf(pr[it][6]-qb.z, 0.f);
      float r7 = fmaxf(pr[it][7]-qb.w, 0.f);
      uint4v wv;
      wv.x = pkbf(r0,r1); wv.y = pkbf(r2,r3);
      wv.z = pkbf(r4,r5); wv.w = pkbf(r6,r7);
      int n = it*32 + (tid >> 3);
      *reinterpret_cast<uint4v*>(&Bs[n*64 + ((cq ^ (n&7))<<3)]) = wv;
    }
  };

  f32x4 acc[4][3];
  #pragma unroll
  for (int mi=0;mi<4;++mi)
    #pragma unroll
    for (int ni=0;ni<3;++ni) acc[mi][ni] = (f32x4){0.f,0.f,0.f,0.f};

  auto mfma_phase = [&](int cur){
    #pragma unroll
    for (int s=0; s<2; ++s){
      short8 av[4], bv[3];
      int c = s*4 + l4;
      #pragma unroll
      for (int mi=0; mi<4; ++mi){
        int row = wr*64 + mi*16 + l15;
        av[mi] = *reinterpret_cast<const short8*>(&As[cur][row*64 + ((c ^ (row&7))<<3)]);
      }
      #pragma unroll
      for (int ni=0; ni<3; ++ni){
        int rown = wc*48 + ni*16 + l15;
        bv[ni] = *reinterpret_cast<const short8*>(&Bs[rown*64 + ((c ^ (rown&7))<<3)]);
      }
      #pragma unroll
      for (int mi=0; mi<4; ++mi)
        #pragma unroll
        for (int ni=0; ni<3; ++ni)
          acc[mi][ni] = __builtin_amdgcn_mfma_f32_16x16x32_bf16(av[mi], bv[ni], acc[mi][ni], 0, 0, 0);
    }
  };

  // prologue: q(j0) + A(j0)
  float4 qe0 = *reinterpret_cast<const float4*>(&qT[(b*NN + j0)*64 + cq*8]);
  float4 qe1 = *reinterpret_cast<const float4*>(&qT[(b*NN + j0)*64 + cq*8 + 4]);
  float4 qo0, qo1;
  stageA(0, j0);

  auto iter = [&](int cur, float4& qa0, float4& qa1, float4& qn0, float4& qn1, int kt){
    int j = j0 + kt;
    if (kt < 47){
      qn0 = *reinterpret_cast<const float4*>(&qT[(b*NN + j + 1)*64 + cq*8]);
      qn1 = *reinterpret_cast<const float4*>(&qT[(b*NN + j + 1)*64 + cq*8 + 4]);
      stageA(cur^1, j+1);
    }
    genB(qa0, qa1);
    if (kt < 47) asm volatile("s_waitcnt vmcnt(6) lgkmcnt(0)" ::: "memory");
    else         asm volatile("s_waitcnt vmcnt(0) lgkmcnt(0)" ::: "memory");
    __builtin_amdgcn_s_barrier();
    mfma_phase(cur);
    __builtin_amdgcn_s_barrier();
  };

  for (int kt2 = 0; kt2 < 48; kt2 += 2){
    iter(0, qe0, qe1, qo0, qo1, kt2);
    iter(1, qo0, qo1, qe0, qe1, kt2+1);
  }

  float* dst = (ks == 0) ? attpx : (attp3 + (size_t)(ks-1)*PART);
  #pragma unroll
  for (int mi=0; mi<4; ++mi){
    #pragma unroll
    for (int r=0; r<4; ++r){
      int o2 = o20 + wr*64 + mi*16 + l4*4 + r;
      #pragma unroll
      for (int ni=0; ni<3; ++ni){
        int n = n0 + wc*48 + ni*16 + l15;
        int idx = (b*CC + o2)*NN + n;
        float v = acc[mi][ni][r];
        if (ks == 0) v += dst[idx];
        dst[idx] = v;
      }
    }
  }
}

// K6: sum 4 partials -> attf + BN stats + fin folded
__global__ __launch_bounds__(256) void k6_stats(
    const float* __restrict__ px, const float* __restrict__ p3,
    float* __restrict__ attf,
    const float* __restrict__ g, const float* __restrict__ be,
    float* __restrict__ scl)
{
  int o2 = blockIdx.x;   // 512
  int tid = threadIdx.x;
  float s=0.f, q=0.f;
  for (int e = tid; e < BB*NN; e += 256){
    int b = e / NN, n = e - b*NN;
    int idx = (b*CC + o2)*NN + n;
    float v = px[idx] + p3[idx] + p3[PART+idx] + p3[2*PART+idx];
    attf[idx] = v;
    s += v; q += v*v;
  }
  __shared__ float rs[4], rq[4];
  #pragma unroll
  for (int off=32; off; off>>=1){ s += __shfl_down(s,off); q += __shfl_down(q,off); }
  int w = tid >> 6;
  if ((tid & 63)==0){ rs[w]=s; rq[w]=q; }
  __syncthreads();
  if (tid==0){
    s = rs[0]+rs[1]+rs[2]+rs[3]; q = rq[0]+rq[1]+rq[2]+rq[3];
    float mean = s * (1.f/3072.f);
    float var = q * (1.f/3072.f) - mean*mean;
    float a = g[o2] * rsqrtf(var + EPSF);
    scl[640+o2] = a;
    scl[1152+o2] = be[o2] - mean*a;
  }
}

// K7: out[b,c] = sum_n sig*x / sum_n sig
__global__ __launch_bounds__(64) void k7_out(
    const float* __restrict__ attf, const float* __restrict__ x,
    const float* __restrict__ scl, float* __restrict__ out)
{
  int row = blockIdx.x;   // 8192
  int b = row >> 9, c = row & 511;
  int t = threadIdx.x;
  float a = scl[640+c], d = scl[1152+c];
  float sf=0.f, ss=0.f;
  #pragma unroll
  for (int it=0;it<3;++it){
    int n = t + it*64;
    float v = attf[b*CC*NN + c*NN + n];
    float sig = 1.f/(1.f + expf(-(a*v + d)));
    sf += sig * x[b*CC*NN + c*NN + n];
    ss += sig;
  }
  #pragma unroll
  for (int off=32; off; off>>=1){ sf+=__shfl_down(sf,off); ss+=__shfl_down(ss,off); }
  if (t==0) out[row] = sf/ss;
}

extern "C" void kernel_launch(void* const* d_in, const int* in_sizes, int n_in,
                              void* d_out, int out_size, void* d_ws, size_t ws_size,
                              hipStream_t stream)
{
  const float* inputs  = (const float*)d_in[0];
  const float* theta_w = (const float*)d_in[2];
  const float* theta_g = (const float*)d_in[4];
  const float* theta_be= (const float*)d_in[5];
  const float* phi_w   = (const float*)d_in[6];
  const float* phi_g   = (const float*)d_in[8];
  const float* phi_be  = (const float*)d_in[9];
  const float* re_w    = (const float*)d_in[10];
  const float* re_g    = (const float*)d_in[12];
  const float* re_be   = (const float*)d_in[13];
  const float* att_w   = (const float*)d_in[14];
  const float* att_g   = (const float*)d_in[16];
  const float* att_be  = (const float*)d_in[17];

  float* ws = (float*)d_ws;
  float* lin2  = ws + OFF_LIN2;
  float* rl    = ws + OFF_RL;
  float* attpx = ws + OFF_ATTPX;
  float* Abuf  = ws + OFF_A;
  float* Bbuf  = ws + OFF_B;
  float* p2buf = ws + OFF_P2;
  float* qTbuf = ws + OFF_QT;
  float* attf  = ws + OFF_ATTF;
  float* attp3 = ws + OFF_ATTP3;
  short* wbf   = (short*)(ws + OFF_WBF);
  short* xT    = (short*)(ws + OFF_XT);
  float* rows  = ws + OFF_ROWS;
  float* scl   = ws + OFF_SCL;

  kconv<<<3200, 256, 0, stream>>>(att_w, wbf);
  kxt<<<384, 256, 0, stream>>>(inputs, xT);
  k1_lin<<<768, 256, 0, stream>>>(inputs, theta_w, phi_w, lin2);
  k2_stats<<<256, 256, 0, stream>>>(lin2, theta_g, theta_be, phi_g, phi_be, scl);
  krelu<<<768, 256, 0, stream>>>(lin2, scl, rl);
  k3_gemm<<<128, 256, 0, stream>>>(rl, re_w, Abuf, Bbuf);
  k3_rows<<<2048, 64, 0, stream>>>(Abuf, Bbuf, rows);
  k4_relstats<<<1, 64, 0, stream>>>(rows, re_g, re_be, scl);
  k4_pq<<<1536, 256, 0, stream>>>(Abuf, Bbuf, scl, p2buf, qTbuf);
  gx_mfma<<<128, 256, 0, stream>>>(wbf, xT, attpx);
  k5_mfma<<<512, 256, 0, stream>>>(wbf, p2buf, qTbuf, attpx, attp3);
  k6_stats<<<512, 256, 0, stream>>>(attpx, attp3, attf, att_g, att_be, scl);
  k7_out<<<8192, 64, 0, stream>>>(attf, inputs, scl, (float*)d_out);
}

// Round 4
// 135.986 us; speedup vs baseline: 5.3813x; 1.1164x over previous
//
#include <hip/hip_runtime.h>

#define BB 16
#define CC 512
#define NN 192
#define CS 128
#define CR 64
#define EPSF 1e-5f
#define PART (BB*CC*NN)                    // 1572864

typedef __attribute__((ext_vector_type(8))) short short8;
typedef __attribute__((ext_vector_type(4))) float f32x4;
typedef __attribute__((ext_vector_type(4))) unsigned int uint4v;

// ---------------- workspace layout (float units) ----------------
#define OFF_LIN2  0                        // 786432 [b][256][192]; dead after k3 -> attpx aliases
#define OFF_ATTPX 0                        // 1572864
#define OFF_A     1572864                  // 196608  A[b][o][i]
#define OFF_B     1769472                  // 196608
#define OFF_P2    1966080                  // 196608  p2[b][n][o]
#define OFF_QT    2162688                  // 196608  qT[b][j][o]
#define OFF_ATTP3 2359296                  // 3*1572864, ends 7077888
#define OFF_WBF   7077888                  // short[512*12800] = 3276800 floats
#define OFF_XT    10354688                 // short[16*192*512] = 786432 floats
#define OFF_ROWS  11141120                 // 16384 (sum 8192 + sq 8192)
#define OFF_SCL   11157504                 // 640

__device__ __forceinline__ unsigned pkbf(float a, float b){
  unsigned r; asm("v_cvt_pk_bf16_f32 %0, %1, %2" : "=v"(r) : "v"(a), "v"(b)); return r;
}

__device__ __forceinline__ void gload_lds16(const void* g, void* l){
  __builtin_amdgcn_global_load_lds(
      (const __attribute__((address_space(1))) unsigned int*)g,
      (__attribute__((address_space(3))) unsigned int*)l, 16, 0, 0);
}

// KCONVXT: att_w -> bf16 wbf (blocks 0..3199); inputs -> xT bf16 [b][n][c] (blocks 3200..3583)
__global__ __launch_bounds__(256) void kconvxt(
    const float* __restrict__ aw, const float* __restrict__ x,
    short* __restrict__ wbf, short* __restrict__ xT)
{
  __shared__ float Ts[64][65];
  if (blockIdx.x < 3200) {
    int t = blockIdx.x*256 + threadIdx.x;     // 819200 threads, 8 elems each
    int o2 = t / 1600;
    int kk = (t - o2*1600) * 8;
    const float* src = &aw[o2*12800 + kk];
    float4 v0 = *reinterpret_cast<const float4*>(src);
    float4 v1 = *reinterpret_cast<const float4*>(src+4);
    uint4v w;
    w.x = pkbf(v0.x, v0.y); w.y = pkbf(v0.z, v0.w);
    w.z = pkbf(v1.x, v1.y); w.w = pkbf(v1.z, v1.w);
    *reinterpret_cast<uint4v*>(&wbf[o2*12800 + kk]) = w;
  } else {
    int bid = blockIdx.x - 3200;    // 384 = b16 * ct8 * nt3
    int nt = bid % 3; int ct = (bid/3) & 7; int b = bid / 24;
    int c0 = ct*64, n0 = nt*64;
    int tid = threadIdx.x;
    int col = tid & 63, r0 = tid >> 6;
    #pragma unroll
    for (int it = 0; it < 16; ++it){
      int r = r0 + it*4;
      Ts[r][col] = x[(b*CC + c0 + r)*NN + n0 + col];
    }
    __syncthreads();
    #pragma unroll
    for (int it = 0; it < 2; ++it){
      int cp = it*256 + tid;
      int nr = cp >> 3, cc8 = (cp & 7)*8;
      uint4v wv;
      wv.x = pkbf(Ts[cc8+0][nr], Ts[cc8+1][nr]);
      wv.y = pkbf(Ts[cc8+2][nr], Ts[cc8+3][nr]);
      wv.z = pkbf(Ts[cc8+4][nr], Ts[cc8+5][nr]);
      wv.w = pkbf(Ts[cc8+6][nr], Ts[cc8+7][nr]);
      *reinterpret_cast<uint4v*>(&xT[((b*NN) + n0 + nr)*CC + c0 + cc8]) = wv;
    }
  }
}

// K1: lin2[b][path*128+cs][n] = sum_c W[cs,c]*x[b,c,n]  (f32, 64x64 tile, 4x4/thread)
__global__ __launch_bounds__(256) void k1_lin(
    const float* __restrict__ x, const float* __restrict__ wth,
    const float* __restrict__ wph, float* __restrict__ lin2)
{
  int bid = blockIdx.x;            // 192 = path2 * b16 * ch2 * nt3
  int nt = bid % 3; int ch = (bid/3) & 1; int b = (bid/6) & 15; int path = bid/96;
  int cs0 = ch*64, n0 = nt*64;
  const float* w = path ? wph : wth;
  int tid = threadIdx.x;
  int ty = tid >> 4, tx = tid & 15;
  __shared__ float Xs[32][64];
  __shared__ float Ws[32][68];
  float acc[4][4];
  #pragma unroll
  for (int i=0;i<4;++i)
    #pragma unroll
    for (int j=0;j<4;++j) acc[i][j]=0.f;
  for (int c0 = 0; c0 < CC; c0 += 32){
    __syncthreads();
    {
      int nn = tid & 63, cb = tid >> 6;
      #pragma unroll
      for (int it = 0; it < 8; ++it)
        Xs[cb + it*4][nn] = x[(b*CC + c0 + cb + it*4)*NN + n0 + nn];
    }
    {
      int cc = tid & 31, sb = tid >> 5;
      #pragma unroll
      for (int it = 0; it < 8; ++it)
        Ws[cc][sb + it*8] = w[(cs0 + sb + it*8)*CC + c0 + cc];
    }
    __syncthreads();
    #pragma unroll 8
    for (int cc = 0; cc < 32; ++cc){
      float w4[4], x4[4];
      *reinterpret_cast<float4*>(w4) = *reinterpret_cast<const float4*>(&Ws[cc][ty*4]);
      *reinterpret_cast<float4*>(x4) = *reinterpret_cast<const float4*>(&Xs[cc][tx*4]);
      #pragma unroll
      for (int i=0;i<4;++i)
        #pragma unroll
        for (int j=0;j<4;++j) acc[i][j] += w4[i]*x4[j];
    }
  }
  #pragma unroll
  for (int r = 0; r < 4; ++r){
    int cs = cs0 + ty*4 + r;
    float4 v = make_float4(acc[r][0],acc[r][1],acc[r][2],acc[r][3]);
    *reinterpret_cast<float4*>(&lin2[(b*256 + path*128 + cs)*NN + n0 + tx*4]) = v;
  }
}

// K2: per-cs2 BN stats over (b,n) -> scl[cs2], scl[256+cs2]
__global__ __launch_bounds__(256) void k2_stats(
    const float* __restrict__ lin2,
    const float* __restrict__ tg, const float* __restrict__ tbe,
    const float* __restrict__ pg, const float* __restrict__ pbe,
    float* __restrict__ scl)
{
  int cs2 = blockIdx.x;            // 256
  const float* src = lin2 + cs2*NN;
  int tid = threadIdx.x;
  float s=0.f, q=0.f;
  for (int e = tid; e < BB*NN; e += 256){
    int b = e / NN, n = e - b*NN;
    float v = src[b*256*NN + n];
    s += v; q += v*v;
  }
  __shared__ float rs[4], rq[4];
  #pragma unroll
  for (int off=32; off; off>>=1){ s += __shfl_down(s,off); q += __shfl_down(q,off); }
  int w = tid >> 6;
  if ((tid & 63)==0){ rs[w]=s; rq[w]=q; }
  __syncthreads();
  if (tid==0){
    s = rs[0]+rs[1]+rs[2]+rs[3]; q = rq[0]+rq[1]+rq[2]+rq[3];
    float mean = s * (1.f/3072.f);
    float var = q * (1.f/3072.f) - mean*mean;
    int path = cs2 >> 7, c = cs2 & 127;
    float g  = path ? pg[c]  : tg[c];
    float be = path ? pbe[c] : tbe[c];
    float a = g * rsqrtf(var + EPSF);
    scl[cs2] = a; scl[256+cs2] = be - mean*a;
  }
}

// K3: A[b,o,i] = sum_c rw[o,c]*relu(bn(lin2_th)); B from ph. BN+relu fused into
// staging; per-row partial sums (over this block's 48 i) in epilogue.
__global__ __launch_bounds__(256) void k3_gemm(
    const float* __restrict__ lin2, const float* __restrict__ scl,
    const float* __restrict__ rw,
    float* __restrict__ A, float* __restrict__ Bq, float* __restrict__ rows4)
{
  int bid = blockIdx.x;            // 128 = path2 * b16 * ih4
  int ih = bid & 3; int b = (bid>>2) & 15; int path = bid >> 6;
  int i0 = ih*48;
  __shared__ float Ls[128][48];
  __shared__ float Ws[64][132];
  int tid = threadIdx.x;
  #pragma unroll
  for (int it = 0; it < 6; ++it){
    int cp = it*256 + tid;         // 1536 float4
    int row = cp / 12, c4 = cp - row*12;
    float a = scl[path*128 + row], d = scl[256 + path*128 + row];
    float4 v = *reinterpret_cast<const float4*>(&lin2[(b*256 + path*128 + row)*NN + i0 + c4*4]);
    float4 r;
    r.x = fmaxf(a*v.x + d, 0.f); r.y = fmaxf(a*v.y + d, 0.f);
    r.z = fmaxf(a*v.z + d, 0.f); r.w = fmaxf(a*v.w + d, 0.f);
    *reinterpret_cast<float4*>(&Ls[row][c4*4]) = r;
  }
  #pragma unroll
  for (int it = 0; it < 8; ++it){
    int cp = it*256 + tid;         // 2048 float4
    int o = cp >> 5, c4 = cp & 31;
    *reinterpret_cast<float4*>(&Ws[o][c4*4]) =
      *reinterpret_cast<const float4*>(&rw[o*CS + c4*4]);
  }
  __syncthreads();
  int oy = tid >> 4, ix = tid & 15;
  float acc[4][3];
  #pragma unroll
  for (int r=0;r<4;++r)
    #pragma unroll
    for (int e=0;e<3;++e) acc[r][e]=0.f;
  #pragma unroll 4
  for (int c = 0; c < 128; ++c){
    float w4[4], l3[3];
    #pragma unroll
    for (int r=0;r<4;++r) w4[r] = Ws[oy*4+r][c];
    #pragma unroll
    for (int e=0;e<3;++e) l3[e] = Ls[c][ix*3+e];
    #pragma unroll
    for (int r=0;r<4;++r)
      #pragma unroll
      for (int e=0;e<3;++e) acc[r][e] += w4[r]*l3[e];
  }
  float* dst = path ? Bq : A;
  #pragma unroll
  for (int r=0;r<4;++r)
    #pragma unroll
    for (int e=0;e<3;++e)
      dst[(b*CR + oy*4+r)*NN + i0 + ix*3 + e] = acc[r][e];
  // partial row sums over this block's 48-column slice
  #pragma unroll
  for (int r=0;r<4;++r){
    float s = acc[r][0]+acc[r][1]+acc[r][2];
    float q = acc[r][0]*acc[r][0]+acc[r][1]*acc[r][1]+acc[r][2]*acc[r][2];
    #pragma unroll
    for (int off=8; off; off>>=1){ s += __shfl_down(s,off,16); q += __shfl_down(q,off,16); }
    if (ix==0){
      int o = oy*4+r;
      int ri = (path*1024 + b*64 + o)*4 + ih;
      rows4[ri] = s; rows4[8192 + ri] = q;
    }
  }
}

// K4a: rel-BN closed form from 4-way partial row sums
__global__ void k4_relstats(const float* __restrict__ rows4,
    const float* __restrict__ rg, const float* __restrict__ rbe,
    float* __restrict__ scl)
{
  int o = threadIdx.x;  // 64
  float sa=0,saq=0,sb=0,sbq=0,cross=0;
  for (int b=0;b<BB;++b){
    float ra=0, rb=0;
    #pragma unroll
    for (int ih=0; ih<4; ++ih){
      int ia = (b*64+o)*4 + ih, ib = (1024 + b*64+o)*4 + ih;
      ra += rows4[ia]; rb += rows4[ib];
      saq += rows4[8192 + ia]; sbq += rows4[8192 + ib];
    }
    sa += ra; sb += rb; cross += ra*rb;
  }
  float mean = (sa - sb) * (1.f/3072.f);
  float e2 = (saq + sbq) * (1.f/3072.f) - cross * (2.f/589824.f);
  float var = e2 - mean*mean;
  float s = rg[o] * rsqrtf(var + EPSF);
  scl[512+o] = s;
  scl[576+o] = rbe[o] - s*mean;
}

// K4b: p2[b][n][o] = s*A[b][o][n] + sh ; qT[b][j][o] = s*B[b][o][j]
__global__ __launch_bounds__(256) void k4_pq(
    const float* __restrict__ A, const float* __restrict__ Bq,
    const float* __restrict__ scl, float* __restrict__ p2,
    float* __restrict__ qT)
{
  int idx = blockIdx.x*256 + threadIdx.x;  // 1536 blocks
  const int TOT = BB*CR*NN;
  int path = idx / TOT; int e = idx - path*TOT;
  int b = e / (CR*NN); int rem = e - b*(CR*NN);
  if (path == 0) {
    int n = rem >> 6, o = rem & 63;
    p2[e] = scl[512+o]*A[b*CR*NN + o*NN + n] + scl[576+o];
  } else {
    int j = rem >> 6, o = rem & 63;
    qT[e] = scl[512+o]*Bq[b*CR*NN + o*NN + j];
  }
}

// K5: att GEMM (x-part + rel-part), bf16 MFMA, r2-proven single-buffer structure.
// Each ks-quarter: 2 x-k-tiles (cols ks*128..) + 48 rel j-tiles -> 50 balanced iters.
__global__ __launch_bounds__(256) void k5_mfma(
    const short* __restrict__ wbf, const short* __restrict__ xT,
    const float* __restrict__ p2, const float* __restrict__ qT,
    float* __restrict__ attpx, float* __restrict__ attp3)
{
  int bid = blockIdx.x;            // 512 = ks4 * b16 * mt4 * nt2
  int nt = bid & 1, mt = (bid >> 1) & 3, b = (bid >> 3) & 15, ks = bid >> 7;
  int o20 = mt*128, n0 = nt*96;
  int j0 = ks*48;

  int tid = threadIdx.x;
  int w = tid >> 6, lane = tid & 63;
  int wr = w >> 1, wc = w & 1;
  int l15 = lane & 15, l4 = lane >> 4;
  int cq = tid & 7;

  __shared__ __align__(16) short As[128*64];
  __shared__ __align__(16) short Bs[96*64];
  __shared__ __align__(16) float qlds[2][64];

  // register-resident p (3 chunks of 8)
  float pr[3][8];
  #pragma unroll
  for (int it=0; it<3; ++it){
    int n = it*32 + (tid >> 3);
    const float* pp = &p2[((b*NN) + n0 + n)*64 + cq*8];
    float4 u0 = *reinterpret_cast<const float4*>(pp);
    float4 u1 = *reinterpret_cast<const float4*>(pp+4);
    pr[it][0]=u0.x; pr[it][1]=u0.y; pr[it][2]=u0.z; pr[it][3]=u0.w;
    pr[it][4]=u1.x; pr[it][5]=u1.y; pr[it][6]=u1.z; pr[it][7]=u1.w;
  }
  if (tid < 64) qlds[0][tid] = qT[(b*NN + j0)*64 + tid];

  auto stageA = [&](int colbase){
    #pragma unroll
    for (int it=0; it<4; ++it){
      int cp = w*256 + it*64 + lane;
      int row = cp >> 3, c = (cp & 7) ^ (row & 7);
      gload_lds16(&wbf[(o20 + row)*12800 + colbase + c*8],
                  &As[(w*256 + it*64)*8]);
    }
  };
  auto stageBx = [&](int colbase){
    #pragma unroll
    for (int it=0; it<3; ++it){
      int cp = w*192 + it*64 + lane;
      int row = cp >> 3, c = (cp & 7) ^ (row & 7);
      gload_lds16(&xT[((b*NN) + n0 + row)*CC + colbase + c*8],
                  &Bs[(w*192 + it*64)*8]);
    }
  };

  f32x4 acc[4][3];
  #pragma unroll
  for (int mi=0;mi<4;++mi)
    #pragma unroll
    for (int ni=0;ni<3;++ni) acc[mi][ni] = (f32x4){0.f,0.f,0.f,0.f};

  auto mfma_phase = [&](){
    #pragma unroll
    for (int s=0; s<2; ++s){
      short8 av[4], bv[3];
      int c = s*4 + l4;
      #pragma unroll
      for (int mi=0; mi<4; ++mi){
        int row = wr*64 + mi*16 + l15;
        av[mi] = *reinterpret_cast<const short8*>(&As[row*64 + ((c ^ (row&7))<<3)]);
      }
      #pragma unroll
      for (int ni=0; ni<3; ++ni){
        int rown = wc*48 + ni*16 + l15;
        bv[ni] = *reinterpret_cast<const short8*>(&Bs[rown*64 + ((c ^ (rown&7))<<3)]);
      }
      #pragma unroll
      for (int mi=0; mi<4; ++mi)
        #pragma unroll
        for (int ni=0; ni<3; ++ni)
          acc[mi][ni] = __builtin_amdgcn_mfma_f32_16x16x32_bf16(av[mi], bv[ni], acc[mi][ni], 0, 0, 0);
    }
  };

  // x-part: 2 k-tiles of the first 512 columns
  for (int kt = 0; kt < 2; ++kt){
    __syncthreads();
    stageA(ks*128 + kt*64);
    stageBx(ks*128 + kt*64);
    __syncthreads();
    mfma_phase();
  }
  // rel part: 48 j-tiles
  for (int kt = 0; kt < 48; ++kt){
    int j = j0 + kt;
    __syncthreads();
    stageA(512 + j*64);
    if (tid < 64 && kt < 47) qlds[(kt+1)&1][tid] = qT[(b*NN + j + 1)*64 + tid];
    {
      const float* qq = qlds[kt&1];
      float4 qa = *reinterpret_cast<const float4*>(&qq[cq*8]);
      float4 qb = *reinterpret_cast<const float4*>(&qq[cq*8+4]);
      #pragma unroll
      for (int it=0; it<3; ++it){
        float r0 = fmaxf(pr[it][0]-qa.x, 0.f);
        float r1 = fmaxf(pr[it][1]-qa.y, 0.f);
        float r2 = fmaxf(pr[it][2]-qa.z, 0.f);
        float r3 = fmaxf(pr[it][3]-qa.w, 0.f);
        float r4 = fmaxf(pr[it][4]-qb.x, 0.f);
        float r5 = fmaxf(pr[it][5]-qb.y, 0.f);
        float r6 = fmaxf(pr[it][6]-qb.z, 0.f);
        float r7 = fmaxf(pr[it][7]-qb.w, 0.f);
        uint4v wv;
        wv.x = pkbf(r0,r1); wv.y = pkbf(r2,r3);
        wv.z = pkbf(r4,r5); wv.w = pkbf(r6,r7);
        int n = it*32 + (tid >> 3);
        *reinterpret_cast<uint4v*>(&Bs[n*64 + ((cq ^ (n&7))<<3)]) = wv;
      }
    }
    __syncthreads();
    mfma_phase();
  }

  float* dst = (ks == 0) ? attpx : (attp3 + (size_t)(ks-1)*PART);
  #pragma unroll
  for (int mi=0; mi<4; ++mi){
    #pragma unroll
    for (int r=0; r<4; ++r){
      int o2 = o20 + wr*64 + mi*16 + l4*4 + r;
      #pragma unroll
      for (int ni=0; ni<3; ++ni){
        int n = n0 + wc*48 + ni*16 + l15;
        dst[(b*CC + o2)*NN + n] = acc[mi][ni][r];
      }
    }
  }
}

// K67: per-channel o2: sum 4 partials (in regs) -> BN stats -> sigmoid ->
// weighted sums -> out[b, o2]. One block per channel; 16 threads per b.
__global__ __launch_bounds__(256) void k67(
    const float* __restrict__ px, const float* __restrict__ p3,
    const float* __restrict__ x,
    const float* __restrict__ g, const float* __restrict__ be,
    float* __restrict__ out)
{
  int o2 = blockIdx.x;   // 512
  int tid = threadIdx.x;
  int b = tid >> 4, nl = tid & 15;
  int base = (b*CC + o2)*NN + nl;
  float v[12], xv[12];
  float s=0.f, q=0.f;
  #pragma unroll
  for (int it=0; it<12; ++it){
    int idx = base + it*16;
    float t = px[idx] + p3[idx] + p3[PART+idx] + p3[2*PART+idx];
    v[it] = t; s += t; q += t*t;
    xv[it] = x[idx];
  }
  __shared__ float rs[4], rq[4], ad[2];
  #pragma unroll
  for (int off=32; off; off>>=1){ s += __shfl_down(s,off); q += __shfl_down(q,off); }
  int w = tid >> 6;
  if ((tid & 63)==0){ rs[w]=s; rq[w]=q; }
  __syncthreads();
  if (tid==0){
    s = rs[0]+rs[1]+rs[2]+rs[3]; q = rq[0]+rq[1]+rq[2]+rq[3];
    float mean = s * (1.f/3072.f);
    float var = q * (1.f/3072.f) - mean*mean;
    float a = g[o2] * rsqrtf(var + EPSF);
    ad[0] = a; ad[1] = be[o2] - mean*a;
  }
  __syncthreads();
  float a = ad[0], d = ad[1];
  float sf=0.f, ss=0.f;
  #pragma unroll
  for (int it=0; it<12; ++it){
    float sig = 1.f/(1.f + expf(-(a*v[it] + d)));
    sf += sig * xv[it]; ss += sig;
  }
  #pragma unroll
  for (int off=8; off; off>>=1){ sf += __shfl_down(sf,off,16); ss += __shfl_down(ss,off,16); }
  if (nl==0) out[b*CC + o2] = sf/ss;
}

extern "C" void kernel_launch(void* const* d_in, const int* in_sizes, int n_in,
                              void* d_out, int out_size, void* d_ws, size_t ws_size,
                              hipStream_t stream)
{
  const float* inputs  = (const float*)d_in[0];
  const float* theta_w = (const float*)d_in[2];
  const float* theta_g = (const float*)d_in[4];
  const float* theta_be= (const float*)d_in[5];
  const float* phi_w   = (const float*)d_in[6];
  const float* phi_g   = (const float*)d_in[8];
  const float* phi_be  = (const float*)d_in[9];
  const float* re_w    = (const float*)d_in[10];
  const float* re_g    = (const float*)d_in[12];
  const float* re_be   = (const float*)d_in[13];
  const float* att_w   = (const float*)d_in[14];
  const float* att_g   = (const float*)d_in[16];
  const float* att_be  = (const float*)d_in[17];

  float* ws = (float*)d_ws;
  float* lin2  = ws + OFF_LIN2;
  float* attpx = ws + OFF_ATTPX;
  float* Abuf  = ws + OFF_A;
  float* Bbuf  = ws + OFF_B;
  float* p2buf = ws + OFF_P2;
  float* qTbuf = ws + OFF_QT;
  float* attp3 = ws + OFF_ATTP3;
  short* wbf   = (short*)(ws + OFF_WBF);
  short* xT    = (short*)(ws + OFF_XT);
  float* rows4 = ws + OFF_ROWS;
  float* scl   = ws + OFF_SCL;

  kconvxt<<<3584, 256, 0, stream>>>(att_w, inputs, wbf, xT);
  k1_lin<<<192, 256, 0, stream>>>(inputs, theta_w, phi_w, lin2);
  k2_stats<<<256, 256, 0, stream>>>(lin2, theta_g, theta_be, phi_g, phi_be, scl);
  k3_gemm<<<128, 256, 0, stream>>>(lin2, scl, re_w, Abuf, Bbuf, rows4);
  k4_relstats<<<1, 64, 0, stream>>>(rows4, re_g, re_be, scl);
  k4_pq<<<1536, 256, 0, stream>>>(Abuf, Bbuf, scl, p2buf, qTbuf);
  k5_mfma<<<512, 256, 0, stream>>>(wbf, xT, p2buf, qTbuf, attpx, attp3);
  k67<<<512, 256, 0, stream>>>(attpx, attp3, inputs, att_g, att_be, (float*)d_out);
}